// Round 2
// baseline (134.855 us; speedup 1.0000x reference)
//
#include <hip/hip_runtime.h>
#include <hip/hip_bf16.h>

// out[i] = y[i] * w[idx] + b[idx],  idx = (t<<10) | bits of x row (MSB first).
// N = 2,000,000 = 128 * 15625 (exact), INPUT_DIM = 10, C = 2048.
// Memory-bound: ~104 MB traffic -> ~17 us floor at 6.3 TB/s achievable.
//
// Strategy:
//  - x staged to LDS via global_load_lds (16B/lane): coalesced HBM access,
//    no VGPR round-trip. 128-row tiles = 5120 B = 5 x 1024 B chunks/wave.
//  - w/b tables (16 KB) staged to LDS once per block -> gathers are LDS
//    reads with ~2-way random conflicts instead of scattered VMEM.
//  - index packed with 10 fmaf(v,2,xj) + 1 cvt (exact for values < 2048).

#define D          10
#define C_TAB      2048
#define TILE_ROWS  128
#define BLOCKS     1024
#define WPB        4        // waves per block

__device__ __forceinline__ void async_load16(const void* g, void* l) {
    __builtin_amdgcn_global_load_lds(
        (const __attribute__((address_space(1))) void*)g,
        (__attribute__((address_space(3))) void*)l, 16, 0, 0);
}

__device__ __forceinline__ int make_idx(const float* row, float tt) {
    const float2* p = (const float2*)row;   // 8B-aligned (row stride 40 B)
    float2 a0 = p[0], a1 = p[1], a2 = p[2], a3 = p[3], a4 = p[4];
    float v = a0.x;
    v = fmaf(v, 2.f, a0.y);
    v = fmaf(v, 2.f, a1.x);
    v = fmaf(v, 2.f, a1.y);
    v = fmaf(v, 2.f, a2.x);
    v = fmaf(v, 2.f, a2.y);
    v = fmaf(v, 2.f, a3.x);
    v = fmaf(v, 2.f, a3.y);
    v = fmaf(v, 2.f, a4.x);
    v = fmaf(v, 2.f, a4.y);
    v = fmaf(tt, 1024.f, v);   // t is the MSB
    return (int)v;
}

__global__ __launch_bounds__(256, 4) void enc_kernel(
    const float* __restrict__ x,   // [N,10] binary
    const float* __restrict__ t,   // [N]
    const float* __restrict__ y,   // [N]
    const float* __restrict__ w,   // [2048]
    const float* __restrict__ b,   // [2048]
    float* __restrict__ out,       // [N]
    int nTiles, int nTotalWaves)
{
    __shared__ float lw[C_TAB];                    // 8 KB
    __shared__ float lb[C_TAB];                    // 8 KB
    __shared__ float xs[WPB][TILE_ROWS * D];       // 4 x 5120 B = 20 KB

    const int tid = threadIdx.x;

    // Stage w/b tables: 2048 floats each = 512 float4; 256 threads x 2.
    {
        const float4* w4 = (const float4*)w;
        const float4* b4 = (const float4*)b;
        float4* lw4 = (float4*)lw;
        float4* lb4 = (float4*)lb;
        lw4[tid]       = w4[tid];
        lw4[tid + 256] = w4[tid + 256];
        lb4[tid]       = b4[tid];
        lb4[tid + 256] = b4[tid + 256];
    }
    __syncthreads();

    const int wave = tid >> 6;
    const int lane = tid & 63;
    float* xw = xs[wave];

    for (int tile = blockIdx.x * WPB + wave; tile < nTiles; tile += nTotalWaves) {
        // Stage 128 rows (5120 B) of x: 5 chunks of 1024 B, lane*16 scatter.
        const char* gbase = (const char*)x + (size_t)tile * (TILE_ROWS * D * 4);
        #pragma unroll
        for (int k = 0; k < 5; ++k) {
            async_load16(gbase + k * 1024 + lane * 16, (char*)xw + k * 1024);
        }

        const int r0 = tile * TILE_ROWS + lane;
        const int r1 = r0 + 64;
        float t0 = t[r0], t1 = t[r1];
        float y0 = y[r0], y1 = y[r1];

        __builtin_amdgcn_s_waitcnt(0);          // drain LDS-DMA (+ t/y loads)
        __asm__ volatile("" ::: "memory");

        const int i0 = make_idx(&xw[lane * D], t0);
        const int i1 = make_idx(&xw[(lane + 64) * D], t1);

        out[r0] = fmaf(y0, lw[i0], lb[i0]);
        out[r1] = fmaf(y1, lw[i1], lb[i1]);
    }
}

// Fallback for a non-multiple-of-128 tail (not hit at N=2,000,000).
__global__ __launch_bounds__(256) void enc_tail(
    const float* __restrict__ x, const float* __restrict__ t,
    const float* __restrict__ y, const float* __restrict__ w,
    const float* __restrict__ b, float* __restrict__ out,
    int start, int n)
{
    int i = start + blockIdx.x * blockDim.x + threadIdx.x;
    if (i >= n) return;
    const float* r = x + (size_t)i * D;
    float v = r[0];
    #pragma unroll
    for (int j = 1; j < D; ++j) v = fmaf(v, 2.f, r[j]);
    int idx = (int)fmaf(t[i], 1024.f, v);
    out[i] = fmaf(y[i], w[idx], b[idx]);
}

extern "C" void kernel_launch(void* const* d_in, const int* in_sizes, int n_in,
                              void* d_out, int out_size, void* d_ws, size_t ws_size,
                              hipStream_t stream) {
    const float* x = (const float*)d_in[0];
    const float* t = (const float*)d_in[1];
    const float* y = (const float*)d_in[2];
    const float* w = (const float*)d_in[3];
    const float* b = (const float*)d_in[4];
    float* out = (float*)d_out;

    const int n = out_size;            // 2,000,000
    const int nTiles = n / TILE_ROWS;  // 15625, exact for this problem
    const int rem = n - nTiles * TILE_ROWS;

    enc_kernel<<<BLOCKS, 256, 0, stream>>>(x, t, y, w, b, out,
                                           nTiles, BLOCKS * WPB);
    if (rem > 0) {
        enc_tail<<<(rem + 255) / 256, 256, 0, stream>>>(
            x, t, y, w, b, out, nTiles * TILE_ROWS, n);
    }
}